// Round 1
// baseline (299.644 us; speedup 1.0000x reference)
//
#include <hip/hip_runtime.h>
#include <cstdint>

// Problem constants (from reference)
constexpr int B_   = 4096;
constexpr int T_   = 512;
constexpr int DIN  = 10;
constexpr int H_   = 20;
constexpr int DOUT = 2;

constexpr int SPW = 3;   // samples per wave (3 x 20 = 60 active lanes of 64)
constexpr int CH  = 8;   // timesteps per x-chunk (8*10 floats = 20 float4, aligned)

__device__ __forceinline__ float fast_tanh(float v) {
    // tanh(v) = 1 - 2/(exp(2v)+1); exact saturation at +/-inf
    float e = __expf(2.0f * v);
    float r = __fdividef(2.0f, e + 1.0f);
    return 1.0f - r;
}

extern "C" __global__ void __launch_bounds__(64, 1)
rnn_fused(const float* __restrict__ x,
          const float* __restrict__ w_ih0, const float* __restrict__ w_hh0,
          const float* __restrict__ b_ih0, const float* __restrict__ b_hh0,
          const float* __restrict__ w_ih1, const float* __restrict__ w_hh1,
          const float* __restrict__ b_ih1, const float* __restrict__ b_hh1,
          const float* __restrict__ fc_w, const float* __restrict__ fc_b,
          float* __restrict__ out)
{
    const int lane = threadIdx.x;
    const int sl   = lane / H_;          // 0..2 active, 3 = idle lanes 60..63
    const int i    = lane - sl * H_;     // h-index 0..19
    const int samp = blockIdx.x * SPW + sl;
    const int sc   = (samp < B_) ? samp : (B_ - 1);   // clamped for safe loads
    const int slc  = (sl < SPW) ? sl : SPW;           // idle lanes use spare LDS row

    __shared__ __align__(16) float h1s[SPW + 1][H_];
    __shared__ __align__(16) float h2s[SPW + 1][H_];

    // ---- per-lane weight rows in registers ----
    float wi0[DIN];
    {
        const float2* p = reinterpret_cast<const float2*>(w_ih0 + i * DIN); // 8B aligned
        #pragma unroll
        for (int k = 0; k < DIN / 2; ++k) {
            float2 v = p[k];
            wi0[2 * k] = v.x; wi0[2 * k + 1] = v.y;
        }
    }
    float wh0[H_], wi1[H_], wh1[H_];
    {
        const float4* p0 = reinterpret_cast<const float4*>(w_hh0 + i * H_); // 16B aligned
        const float4* p1 = reinterpret_cast<const float4*>(w_ih1 + i * H_);
        const float4* p2 = reinterpret_cast<const float4*>(w_hh1 + i * H_);
        #pragma unroll
        for (int k = 0; k < H_ / 4; ++k) {
            float4 a = p0[k]; wh0[4*k]=a.x; wh0[4*k+1]=a.y; wh0[4*k+2]=a.z; wh0[4*k+3]=a.w;
            float4 b = p1[k]; wi1[4*k]=b.x; wi1[4*k+1]=b.y; wi1[4*k+2]=b.z; wi1[4*k+3]=b.w;
            float4 c = p2[k]; wh1[4*k]=c.x; wh1[4*k+1]=c.y; wh1[4*k+2]=c.z; wh1[4*k+3]=c.w;
        }
    }
    const float bias0 = b_ih0[i] + b_hh0[i];
    const float bias1 = b_ih1[i] + b_hh1[i];

    float h1[H_], h2[H_];
    #pragma unroll
    for (int j = 0; j < H_; ++j) { h1[j] = 0.0f; h2[j] = 0.0f; }

    const float4* xb = reinterpret_cast<const float4*>(x + (size_t)sc * (T_ * DIN));

    for (int t0 = 0; t0 < T_; t0 += CH) {
        // ---- x-projection for the next CH steps (amortized, aligned float4) ----
        float xp[CH];
        #pragma unroll
        for (int m = 0; m < CH; ++m) xp[m] = bias0;
        #pragma unroll
        for (int k = 0; k < (CH * DIN) / 4; ++k) {
            float4 v = xb[(t0 * DIN) / 4 + k];
            float el0 = v.x, el1 = v.y, el2 = v.z, el3 = v.w;
            int idx = 4 * k;
            xp[(idx+0)/DIN] = fmaf(el0, wi0[(idx+0)%DIN], xp[(idx+0)/DIN]);
            xp[(idx+1)/DIN] = fmaf(el1, wi0[(idx+1)%DIN], xp[(idx+1)/DIN]);
            xp[(idx+2)/DIN] = fmaf(el2, wi0[(idx+2)%DIN], xp[(idx+2)/DIN]);
            xp[(idx+3)/DIN] = fmaf(el3, wi0[(idx+3)%DIN], xp[(idx+3)/DIN]);
        }

        #pragma unroll
        for (int m = 0; m < CH; ++m) {
            // ---- layer 0: a = xp + h1 . w_hh0[i,:] ----
            float a0 = xp[m], a1 = 0.f, a2 = 0.f, a3 = 0.f;
            #pragma unroll
            for (int j = 0; j < H_; j += 4) {
                a0 = fmaf(h1[j+0], wh0[j+0], a0);
                a1 = fmaf(h1[j+1], wh0[j+1], a1);
                a2 = fmaf(h1[j+2], wh0[j+2], a2);
                a3 = fmaf(h1[j+3], wh0[j+3], a3);
            }
            float h1n = fast_tanh((a0 + a1) + (a2 + a3));

            __syncthreads();                 // WAR: prior reads of h1s done
            h1s[slc][i] = h1n;
            __syncthreads();                 // RAW: writes visible
            #pragma unroll
            for (int k = 0; k < H_ / 4; ++k) {
                float4 v = reinterpret_cast<const float4*>(&h1s[slc][0])[k];
                h1[4*k]=v.x; h1[4*k+1]=v.y; h1[4*k+2]=v.z; h1[4*k+3]=v.w;
            }

            // ---- layer 1: b = bias1 + h1 . w_ih1[i,:] + h2 . w_hh1[i,:] ----
            float b0 = bias1, b1 = 0.f, b2 = 0.f, b3 = 0.f;
            #pragma unroll
            for (int j = 0; j < H_; j += 4) {
                b0 = fmaf(h1[j+0], wi1[j+0], b0);
                b1 = fmaf(h1[j+1], wi1[j+1], b1);
                b2 = fmaf(h1[j+2], wi1[j+2], b2);
                b3 = fmaf(h1[j+3], wi1[j+3], b3);
            }
            #pragma unroll
            for (int j = 0; j < H_; j += 4) {
                b0 = fmaf(h2[j+0], wh1[j+0], b0);
                b1 = fmaf(h2[j+1], wh1[j+1], b1);
                b2 = fmaf(h2[j+2], wh1[j+2], b2);
                b3 = fmaf(h2[j+3], wh1[j+3], b3);
            }
            float h2n = fast_tanh((b0 + b1) + (b2 + b3));

            __syncthreads();
            h2s[slc][i] = h2n;
            __syncthreads();
            #pragma unroll
            for (int k = 0; k < H_ / 4; ++k) {
                float4 v = reinterpret_cast<const float4*>(&h2s[slc][0])[k];
                h2[4*k]=v.x; h2[4*k+1]=v.y; h2[4*k+2]=v.z; h2[4*k+3]=v.w;
            }
        }
    }

    // ---- FC epilogue: lanes i<2 hold full h2; out[samp][i] ----
    if (sl < SPW && samp < B_ && i < DOUT) {
        float acc = fc_b[i];
        #pragma unroll
        for (int j = 0; j < H_; ++j) acc = fmaf(h2[j], fc_w[i * H_ + j], acc);
        out[samp * DOUT + i] = acc;
    }
}

extern "C" void kernel_launch(void* const* d_in, const int* in_sizes, int n_in,
                              void* d_out, int out_size, void* d_ws, size_t ws_size,
                              hipStream_t stream) {
    (void)in_sizes; (void)n_in; (void)d_ws; (void)ws_size; (void)out_size;
    const float* x     = (const float*)d_in[0];
    const float* w_ih0 = (const float*)d_in[1];
    const float* w_hh0 = (const float*)d_in[2];
    const float* b_ih0 = (const float*)d_in[3];
    const float* b_hh0 = (const float*)d_in[4];
    const float* w_ih1 = (const float*)d_in[5];
    const float* w_hh1 = (const float*)d_in[6];
    const float* b_ih1 = (const float*)d_in[7];
    const float* b_hh1 = (const float*)d_in[8];
    const float* fc_w  = (const float*)d_in[9];
    const float* fc_b  = (const float*)d_in[10];
    float* out = (float*)d_out;

    const int grid = (B_ + SPW - 1) / SPW;   // 1366 single-wave blocks
    hipLaunchKernelGGL(rnn_fused, dim3(grid), dim3(64), 0, stream,
                       x, w_ih0, w_hh0, b_ih0, b_hh0,
                       w_ih1, w_hh1, b_ih1, b_hh1, fc_w, fc_b, out);
}

// Round 2
// 189.510 us; speedup vs baseline: 1.5811x; 1.5811x over previous
//
#include <hip/hip_runtime.h>
#include <cstdint>

// Problem constants (from reference)
constexpr int B_   = 4096;
constexpr int T_   = 512;
constexpr int DIN  = 10;
constexpr int H_   = 20;
constexpr int DOUT = 2;

constexpr int SPW = 3;            // samples per wave (3 x 20 = 60 active lanes)
constexpr int CH  = 4;            // timesteps per x-chunk (4*10 floats = 10 float4)
constexpr int XV  = CH * DIN / 4; // float4 regs per chunk

// Compiler-only memory fence: pins LDS op ordering for wave-synchronous
// exchange (single-wave workgroup; same-wave DS ops execute in order in HW).
#define CFENCE() asm volatile("" ::: "memory")

__device__ __forceinline__ float fast_tanh(float v) {
    // tanh(v) = 1 - 2/(exp(2v)+1); exact saturation at +/-inf
    float e = __expf(2.0f * v);
    return 1.0f - __fdividef(2.0f, e + 1.0f);
}

extern "C" __global__ void __launch_bounds__(64, 1)
rnn_fused(const float* __restrict__ x,
          const float* __restrict__ w_ih0, const float* __restrict__ w_hh0,
          const float* __restrict__ b_ih0, const float* __restrict__ b_hh0,
          const float* __restrict__ w_ih1, const float* __restrict__ w_hh1,
          const float* __restrict__ b_ih1, const float* __restrict__ b_hh1,
          const float* __restrict__ fc_w, const float* __restrict__ fc_b,
          float* __restrict__ out)
{
    const int lane = threadIdx.x;
    const int sl   = lane / H_;          // 0..2 active, 3 = idle lanes 60..63
    const int i    = lane - sl * H_;     // h-index 0..19
    const int samp = blockIdx.x * SPW + sl;
    const int sc   = (samp < B_) ? samp : (B_ - 1);   // clamped for safe loads
    const int slc  = (sl < SPW) ? sl : SPW;           // idle lanes -> spare row

    __shared__ __align__(16) float h1s[SPW + 1][H_];
    __shared__ __align__(16) float h2s[SPW + 1][H_];

    // ---- per-lane weight rows in registers ----
    float wi0[DIN];
    {
        const float2* p = reinterpret_cast<const float2*>(w_ih0 + i * DIN);
        #pragma unroll
        for (int k = 0; k < DIN / 2; ++k) {
            float2 v = p[k];
            wi0[2 * k] = v.x; wi0[2 * k + 1] = v.y;
        }
    }
    float wh0[H_], wi1[H_], wh1[H_];
    {
        const float4* p0 = reinterpret_cast<const float4*>(w_hh0 + i * H_);
        const float4* p1 = reinterpret_cast<const float4*>(w_ih1 + i * H_);
        const float4* p2 = reinterpret_cast<const float4*>(w_hh1 + i * H_);
        #pragma unroll
        for (int k = 0; k < H_ / 4; ++k) {
            float4 a = p0[k]; wh0[4*k]=a.x; wh0[4*k+1]=a.y; wh0[4*k+2]=a.z; wh0[4*k+3]=a.w;
            float4 b = p1[k]; wi1[4*k]=b.x; wi1[4*k+1]=b.y; wi1[4*k+2]=b.z; wi1[4*k+3]=b.w;
            float4 c = p2[k]; wh1[4*k]=c.x; wh1[4*k+1]=c.y; wh1[4*k+2]=c.z; wh1[4*k+3]=c.w;
        }
    }
    const float bias0 = b_ih0[i] + b_hh0[i];
    const float bias1 = b_ih1[i] + b_hh1[i];

    float h1[H_], h2[H_];
    #pragma unroll
    for (int j = 0; j < H_; ++j) { h1[j] = 0.0f; h2[j] = 0.0f; }

    const float4* xb = reinterpret_cast<const float4*>(x + (size_t)sc * (T_ * DIN));

    // ---- prologue: load chunk 0 into prefetch regs ----
    float4 xv[XV];
    #pragma unroll
    for (int k = 0; k < XV; ++k) xv[k] = xb[k];

    for (int t0 = 0; t0 < T_; t0 += CH) {
        // ---- consume prefetched xv -> xp for this chunk ----
        float xp[CH];
        #pragma unroll
        for (int m = 0; m < CH; ++m) xp[m] = bias0;
        #pragma unroll
        for (int k = 0; k < XV; ++k) {
            int idx = 4 * k;
            xp[(idx+0)/DIN] = fmaf(xv[k].x, wi0[(idx+0)%DIN], xp[(idx+0)/DIN]);
            xp[(idx+1)/DIN] = fmaf(xv[k].y, wi0[(idx+1)%DIN], xp[(idx+1)/DIN]);
            xp[(idx+2)/DIN] = fmaf(xv[k].z, wi0[(idx+2)%DIN], xp[(idx+2)/DIN]);
            xp[(idx+3)/DIN] = fmaf(xv[k].w, wi0[(idx+3)%DIN], xp[(idx+3)/DIN]);
        }

        // ---- issue next chunk's loads (wait lands ~4 steps later) ----
        {
            const int t0n = (t0 + CH < T_) ? (t0 + CH) : 0;  // clamp, branchless
            #pragma unroll
            for (int k = 0; k < XV; ++k) xv[k] = xb[(t0n * DIN) / 4 + k];
        }

        #pragma unroll
        for (int m = 0; m < CH; ++m) {
            // ---- layer 0: a = xp + h1(t-1) . w_hh0[i,:] ----
            float a0 = xp[m], a1 = 0.f, a2 = 0.f, a3 = 0.f;
            #pragma unroll
            for (int j = 0; j < H_; j += 4) {
                a0 = fmaf(h1[j+0], wh0[j+0], a0);
                a1 = fmaf(h1[j+1], wh0[j+1], a1);
                a2 = fmaf(h1[j+2], wh0[j+2], a2);
                a3 = fmaf(h1[j+3], wh0[j+3], a3);
            }
            float h1n = fast_tanh((a0 + a1) + (a2 + a3));

            // ---- h1 exchange (wave-synchronous, no barrier) ----
            CFENCE();
            h1s[slc][i] = h1n;
            CFENCE();

            // overlap the h1s round-trip with the h2(t-1).w_hh1 product
            float b0 = bias1, b1 = 0.f, b2 = 0.f, b3 = 0.f;
            #pragma unroll
            for (int j = 0; j < H_; j += 4) {
                b0 = fmaf(h2[j+0], wh1[j+0], b0);
                b1 = fmaf(h2[j+1], wh1[j+1], b1);
                b2 = fmaf(h2[j+2], wh1[j+2], b2);
                b3 = fmaf(h2[j+3], wh1[j+3], b3);
            }

            #pragma unroll
            for (int k = 0; k < H_ / 4; ++k) {
                float4 v = reinterpret_cast<const float4*>(&h1s[slc][0])[k];
                h1[4*k]=v.x; h1[4*k+1]=v.y; h1[4*k+2]=v.z; h1[4*k+3]=v.w;
            }
            CFENCE();

            // ---- layer 1: b += h1(t) . w_ih1[i,:] ----
            #pragma unroll
            for (int j = 0; j < H_; j += 4) {
                b0 = fmaf(h1[j+0], wi1[j+0], b0);
                b1 = fmaf(h1[j+1], wi1[j+1], b1);
                b2 = fmaf(h1[j+2], wi1[j+2], b2);
                b3 = fmaf(h1[j+3], wi1[j+3], b3);
            }
            float h2n = fast_tanh((b0 + b1) + (b2 + b3));

            // ---- h2 exchange; read-back latency hides under next layer-0 ----
            CFENCE();
            h2s[slc][i] = h2n;
            CFENCE();
            #pragma unroll
            for (int k = 0; k < H_ / 4; ++k) {
                float4 v = reinterpret_cast<const float4*>(&h2s[slc][0])[k];
                h2[4*k]=v.x; h2[4*k+1]=v.y; h2[4*k+2]=v.z; h2[4*k+3]=v.w;
            }
            CFENCE();
        }
    }

    // ---- FC epilogue: lanes i<2 hold full h2; out[samp][i] ----
    if (sl < SPW && samp < B_ && i < DOUT) {
        float acc = fc_b[i];
        #pragma unroll
        for (int j = 0; j < H_; ++j) acc = fmaf(h2[j], fc_w[i * H_ + j], acc);
        out[samp * DOUT + i] = acc;
    }
}

extern "C" void kernel_launch(void* const* d_in, const int* in_sizes, int n_in,
                              void* d_out, int out_size, void* d_ws, size_t ws_size,
                              hipStream_t stream) {
    (void)in_sizes; (void)n_in; (void)d_ws; (void)ws_size; (void)out_size;
    const float* x     = (const float*)d_in[0];
    const float* w_ih0 = (const float*)d_in[1];
    const float* w_hh0 = (const float*)d_in[2];
    const float* b_ih0 = (const float*)d_in[3];
    const float* b_hh0 = (const float*)d_in[4];
    const float* w_ih1 = (const float*)d_in[5];
    const float* w_hh1 = (const float*)d_in[6];
    const float* b_ih1 = (const float*)d_in[7];
    const float* b_hh1 = (const float*)d_in[8];
    const float* fc_w  = (const float*)d_in[9];
    const float* fc_b  = (const float*)d_in[10];
    float* out = (float*)d_out;

    const int grid = (B_ + SPW - 1) / SPW;   // 1366 single-wave blocks
    hipLaunchKernelGGL(rnn_fused, dim3(grid), dim3(64), 0, stream,
                       x, w_ih0, w_hh0, b_ih0, b_hh0,
                       w_ih1, w_hh1, b_ih1, b_hh1, fc_w, fc_b, out);
}

// Round 3
// 167.865 us; speedup vs baseline: 1.7850x; 1.1289x over previous
//
#include <hip/hip_runtime.h>
#include <cstdint>

// Problem constants (from reference)
constexpr int B_   = 4096;
constexpr int T_   = 512;
constexpr int DIN  = 10;
constexpr int H_   = 20;
constexpr int DOUT = 2;

constexpr int SPW = 3;            // samples per wave (3 x 20 = 60 active lanes)
constexpr int CH  = 2;            // timesteps per x-chunk (2*10 floats = 5 float4)
constexpr int XV  = CH * DIN / 4; // float4 prefetch regs per chunk (5 -> 20 VGPRs)

// Compiler-only memory fence: pins LDS op ordering for wave-synchronous
// exchange (single-wave workgroup; same-wave DS ops execute in order in HW).
#define CFENCE() asm volatile("" ::: "memory")

__device__ __forceinline__ float fast_tanh(float v) {
    // tanh(v) = 1 - 2/(exp2(v*2*log2e)+1), fma-folded: 5 VALU ops
    float e = __builtin_amdgcn_exp2f(v * 2.885390082f /* 2*log2(e) */);
    float r = __builtin_amdgcn_rcpf(e + 1.0f);
    return fmaf(-2.0f, r, 1.0f);
}

extern "C" __global__ void __launch_bounds__(64, 2)
rnn_fused(const float* __restrict__ x,
          const float* __restrict__ w_ih0, const float* __restrict__ w_hh0,
          const float* __restrict__ b_ih0, const float* __restrict__ b_hh0,
          const float* __restrict__ w_ih1, const float* __restrict__ w_hh1,
          const float* __restrict__ b_ih1, const float* __restrict__ b_hh1,
          const float* __restrict__ fc_w, const float* __restrict__ fc_b,
          float* __restrict__ out)
{
    const int lane = threadIdx.x;
    const int sl   = lane / H_;          // 0..2 active, 3 = idle lanes 60..63
    const int i    = lane - sl * H_;     // h-index 0..19
    const int samp = blockIdx.x * SPW + sl;
    const int sc   = (samp < B_) ? samp : (B_ - 1);   // clamped for safe loads
    const int slc  = (sl < SPW) ? sl : SPW;           // idle lanes -> spare row

    __shared__ __align__(16) float h1s[SPW + 1][H_];
    __shared__ __align__(16) float h2s[SPW + 1][H_];

    // ---- per-lane weight rows in registers (loop-invariant; must stay resident) ----
    float wi0[DIN];
    {
        const float2* p = reinterpret_cast<const float2*>(w_ih0 + i * DIN);
        #pragma unroll
        for (int k = 0; k < DIN / 2; ++k) {
            float2 v = p[k];
            wi0[2 * k] = v.x; wi0[2 * k + 1] = v.y;
        }
    }
    float wh0[H_], wi1[H_], wh1[H_];
    {
        const float4* p0 = reinterpret_cast<const float4*>(w_hh0 + i * H_);
        const float4* p1 = reinterpret_cast<const float4*>(w_ih1 + i * H_);
        const float4* p2 = reinterpret_cast<const float4*>(w_hh1 + i * H_);
        #pragma unroll
        for (int k = 0; k < H_ / 4; ++k) {
            float4 a = p0[k]; wh0[4*k]=a.x; wh0[4*k+1]=a.y; wh0[4*k+2]=a.z; wh0[4*k+3]=a.w;
            float4 b = p1[k]; wi1[4*k]=b.x; wi1[4*k+1]=b.y; wi1[4*k+2]=b.z; wi1[4*k+3]=b.w;
            float4 c = p2[k]; wh1[4*k]=c.x; wh1[4*k+1]=c.y; wh1[4*k+2]=c.z; wh1[4*k+3]=c.w;
        }
    }
    const float bias0 = b_ih0[i] + b_hh0[i];
    const float bias1 = b_ih1[i] + b_hh1[i];

    float h1[H_], h2[H_];
    #pragma unroll
    for (int j = 0; j < H_; ++j) { h1[j] = 0.0f; h2[j] = 0.0f; }

    const float4* xb = reinterpret_cast<const float4*>(x + (size_t)sc * (T_ * DIN));

    // ---- prologue: prefetch chunk 0 ----
    float4 xv[XV];
    #pragma unroll
    for (int k = 0; k < XV; ++k) xv[k] = xb[k];

    for (int t0 = 0; t0 < T_; t0 += CH) {
        // ---- consume prefetched xv -> xp ----
        float xp[CH];
        #pragma unroll
        for (int m = 0; m < CH; ++m) xp[m] = bias0;
        #pragma unroll
        for (int k = 0; k < XV; ++k) {
            int idx = 4 * k;
            xp[(idx+0)/DIN] = fmaf(xv[k].x, wi0[(idx+0)%DIN], xp[(idx+0)/DIN]);
            xp[(idx+1)/DIN] = fmaf(xv[k].y, wi0[(idx+1)%DIN], xp[(idx+1)/DIN]);
            xp[(idx+2)/DIN] = fmaf(xv[k].z, wi0[(idx+2)%DIN], xp[(idx+2)/DIN]);
            xp[(idx+3)/DIN] = fmaf(xv[k].w, wi0[(idx+3)%DIN], xp[(idx+3)/DIN]);
        }

        // ---- issue next chunk's loads; wait lands ~2 steps (~500cy) later ----
        {
            const int t0n = (t0 + CH < T_) ? (t0 + CH) : 0;  // clamp, branchless
            #pragma unroll
            for (int k = 0; k < XV; ++k) xv[k] = xb[(t0n * DIN) / 4 + k];
        }

        #pragma unroll
        for (int m = 0; m < CH; ++m) {
            // ---- layer 0: a = xp + h1(t-1) . w_hh0[i,:] ----
            float a0 = xp[m], a1 = 0.f, a2 = 0.f, a3 = 0.f;
            #pragma unroll
            for (int j = 0; j < H_; j += 4) {
                a0 = fmaf(h1[j+0], wh0[j+0], a0);
                a1 = fmaf(h1[j+1], wh0[j+1], a1);
                a2 = fmaf(h1[j+2], wh0[j+2], a2);
                a3 = fmaf(h1[j+3], wh0[j+3], a3);
            }
            float h1n = fast_tanh((a0 + a1) + (a2 + a3));

            // ---- h1 exchange (wave-synchronous, no barrier) ----
            CFENCE();
            h1s[slc][i] = h1n;
            CFENCE();

            // overlap the h1s round-trip with the h2(t-1).w_hh1 product
            float b0 = bias1, b1 = 0.f, b2 = 0.f, b3 = 0.f;
            #pragma unroll
            for (int j = 0; j < H_; j += 4) {
                b0 = fmaf(h2[j+0], wh1[j+0], b0);
                b1 = fmaf(h2[j+1], wh1[j+1], b1);
                b2 = fmaf(h2[j+2], wh1[j+2], b2);
                b3 = fmaf(h2[j+3], wh1[j+3], b3);
            }

            #pragma unroll
            for (int k = 0; k < H_ / 4; ++k) {
                float4 v = reinterpret_cast<const float4*>(&h1s[slc][0])[k];
                h1[4*k]=v.x; h1[4*k+1]=v.y; h1[4*k+2]=v.z; h1[4*k+3]=v.w;
            }
            CFENCE();

            // ---- layer 1: b += h1(t) . w_ih1[i,:] ----
            #pragma unroll
            for (int j = 0; j < H_; j += 4) {
                b0 = fmaf(h1[j+0], wi1[j+0], b0);
                b1 = fmaf(h1[j+1], wi1[j+1], b1);
                b2 = fmaf(h1[j+2], wi1[j+2], b2);
                b3 = fmaf(h1[j+3], wi1[j+3], b3);
            }
            float h2n = fast_tanh((b0 + b1) + (b2 + b3));

            // ---- h2 exchange; read-back latency hides under next layer-0 ----
            CFENCE();
            h2s[slc][i] = h2n;
            CFENCE();
            #pragma unroll
            for (int k = 0; k < H_ / 4; ++k) {
                float4 v = reinterpret_cast<const float4*>(&h2s[slc][0])[k];
                h2[4*k]=v.x; h2[4*k+1]=v.y; h2[4*k+2]=v.z; h2[4*k+3]=v.w;
            }
            CFENCE();
        }
    }

    // ---- FC epilogue: lanes i<2 hold full h2; out[samp][i] ----
    if (sl < SPW && samp < B_ && i < DOUT) {
        float acc = fc_b[i];
        #pragma unroll
        for (int j = 0; j < H_; ++j) acc = fmaf(h2[j], fc_w[i * H_ + j], acc);
        out[samp * DOUT + i] = acc;
    }
}

extern "C" void kernel_launch(void* const* d_in, const int* in_sizes, int n_in,
                              void* d_out, int out_size, void* d_ws, size_t ws_size,
                              hipStream_t stream) {
    (void)in_sizes; (void)n_in; (void)d_ws; (void)ws_size; (void)out_size;
    const float* x     = (const float*)d_in[0];
    const float* w_ih0 = (const float*)d_in[1];
    const float* w_hh0 = (const float*)d_in[2];
    const float* b_ih0 = (const float*)d_in[3];
    const float* b_hh0 = (const float*)d_in[4];
    const float* w_ih1 = (const float*)d_in[5];
    const float* w_hh1 = (const float*)d_in[6];
    const float* b_ih1 = (const float*)d_in[7];
    const float* b_hh1 = (const float*)d_in[8];
    const float* fc_w  = (const float*)d_in[9];
    const float* fc_b  = (const float*)d_in[10];
    float* out = (float*)d_out;

    const int grid = (B_ + SPW - 1) / SPW;   // 1366 single-wave blocks
    hipLaunchKernelGGL(rnn_fused, dim3(grid), dim3(64), 0, stream,
                       x, w_ih0, w_hh0, b_ih0, b_hh0,
                       w_ih1, w_hh1, b_ih1, b_hh1, fc_w, fc_b, out);
}